// Round 1
// baseline (710.035 us; speedup 1.0000x reference)
//
#include <hip/hip_runtime.h>

// NNOpenSetClassifier — streaming restructure (R3).
//   frame [8,16384,128] f32, templates [64,16384,128] f32, classes [64] int
// Outputs (concat f32): masked_pred [8,N,21], mask [8,N], ncm [8,N],
//                       min_d [8,N], neigh_classes [8,N]
//
// Structure: block owns P=16 pixels, loops t=0..63 over templates.
//  - template tile tmpl[t][n0:n0+16][:] = 8KB CONTIGUOUS -> coalesced stream,
//    double-buffered in LDS (1 barrier/iter; write targets the other buffer).
//  - frame rows resident in REGISTERS (thread = 2 batches x 32-float d-quarter)
//    -> frame read from HBM exactly once, zero frame LDS traffic.
//  - running min/argmin over ascending t with strict '<'  == jnp.argmin ties.
// Pipe model per CU per iter (4 blocks/CU): HBM ~3200cy > LDS ~2300 > VALU ~1280
//  -> HBM-bound; predicted ~110-150 us vs 730 us for the per-pixel structure.

#define NPIX   16384
#define DDIM   128
#define NT     64
#define NB     8
#define NCAT   21
#define THRESH 230.0f
#define P      16            // pixels per block
#define TSTR   132           // LDS row stride (floats): 128+4 pad, 16B-aligned;
                             // bank quad = (np+kq)&7 -> 8 lanes/quad, full BW

__global__ __launch_bounds__(256, 4) void nn_openset_kernel(
    const float* __restrict__ frame,   // [8, 16384, 128]
    const float* __restrict__ tmpl,    // [64, 16384, 128]
    const int*   __restrict__ tcls,    // [64]
    float* __restrict__ out)
{
    __shared__ __align__(16) float ts[2][P * TSTR];   // 2 x 8448 B

    const int tid = threadIdx.x;
    const int n0  = blockIdx.x * P;

    // thread = (batch-pair bp, pixel np, d-quarter dq)
    const int bp = tid >> 6;          // 0..3  (== wave id)
    const int ln = tid & 63;
    const int np = ln >> 2;           // 0..15 pixel within tile
    const int dq = ln & 3;            // 0..3  d-quarter (32 floats)
    const int b0 = bp * 2, b1 = b0 + 1;
    const int n  = n0 + np;

    // staging map (fixed per thread): tile = 512 float4; q0=tid, q1=tid+256
    const int r0 = tid >> 5;          // rows 0..7
    const int c0 = tid & 31;
    const int w0 = r0 * TSTR + c0 * 4;        // LDS float offset, q0
    const int w1 = (r0 + 8) * TSTR + c0 * 4;  // q1 -> rows 8..15

    // global template stream: advance one t-plane (2 MB) per iteration
    const size_t PLANE4 = (size_t)NPIX * (DDIM / 4);
    const float4* gq = (const float4*)tmpl + (size_t)n0 * (DDIM / 4);

    // issue tile-0 staging loads first...
    float4 s0 = gq[tid];
    float4 s1 = gq[tid + 256];
    gq += PLANE4;

    // ...then frame quarter-rows into registers (2 batches x 32 floats)
    float4 fr0[8], fr1[8];
    {
        const float4* f0 = (const float4*)(frame + ((size_t)b0 * NPIX + n) * DDIM + dq * 32);
        const float4* f1 = (const float4*)(frame + ((size_t)b1 * NPIX + n) * DDIM + dq * 32);
        #pragma unroll
        for (int j = 0; j < 8; ++j) { fr0[j] = f0[j]; fr1[j] = f1[j]; }
    }

    *(float4*)(&ts[0][w0]) = s0;
    *(float4*)(&ts[0][w1]) = s1;
    __syncthreads();

    float vmin0 = 3.402823466e38f, vmin1 = 3.402823466e38f;
    int   imin0 = 0, imin1 = 0;

    for (int t = 0; t < NT; ++t) {
        // prefetch tile t+1 into registers (consumed after compute)
        if (t < NT - 1) { s0 = gq[tid]; s1 = gq[tid + 256]; gq += PLANE4; }

        // compute partial squared distances from tile t
        const float* tsp = &ts[t & 1][np * TSTR + dq * 32];
        float a0 = 0.0f, a1 = 0.0f;
        #pragma unroll
        for (int kq = 0; kq < 8; ++kq) {
            const float4 tv = *(const float4*)(tsp + (kq << 2));  // ds_read_b128
            const float4 x0 = fr0[kq];
            const float4 x1 = fr1[kq];
            float d;
            d = x0.x - tv.x; a0 = fmaf(d, d, a0);
            d = x0.y - tv.y; a0 = fmaf(d, d, a0);
            d = x0.z - tv.z; a0 = fmaf(d, d, a0);
            d = x0.w - tv.w; a0 = fmaf(d, d, a0);
            d = x1.x - tv.x; a1 = fmaf(d, d, a1);
            d = x1.y - tv.y; a1 = fmaf(d, d, a1);
            d = x1.z - tv.z; a1 = fmaf(d, d, a1);
            d = x1.w - tv.w; a1 = fmaf(d, d, a1);
        }
        // combine the 4 d-quarters (lanes np*4+dq): xor 1 then xor 2
        a0 += __shfl_xor(a0, 1);
        a0 += __shfl_xor(a0, 2);
        a1 += __shfl_xor(a1, 1);
        a1 += __shfl_xor(a1, 2);

        // running min/argmin (ascending t, strict '<' => lowest index on ties)
        const bool u0 = a0 < vmin0;
        const bool u1 = a1 < vmin1;
        imin0 = u0 ? t : imin0;  vmin0 = u0 ? a0 : vmin0;
        imin1 = u1 ? t : imin1;  vmin1 = u1 ? a1 : vmin1;

        // write prefetched tile into the OTHER buffer (iter t readers untouched)
        if (t < NT - 1) {
            float* wp = ts[(t + 1) & 1];
            *(float4*)(&wp[w0]) = s0;
            *(float4*)(&wp[w1]) = s1;
        }
        __syncthreads();   // one barrier/iter: publishes buf[(t+1)&1] writes,
                           // closes buf[t&1] reads before iter t+2 overwrites it
    }

    // ---- epilogue: all 4 dq lanes hold identical (vmin, imin); split the writes
    const int  cls0 = tcls[imin0];
    const int  cls1 = tcls[imin1];
    const bool m0 = (vmin0 <= THRESH);
    const bool m1 = (vmin1 <= THRESH);

    float* o0 = out;                                  // masked_pred [8,N,21]
    float* o1 = out + (size_t)NB * NPIX * NCAT;       // mask        [8,N]
    float* o2 = o1 + NB * NPIX;                       // ncm         [8,N]
    float* o3 = o2 + NB * NPIX;                       // min_d       [8,N]
    float* o4 = o3 + NB * NPIX;                       // neigh_cls   [8,N]

    const size_t p0 = (size_t)b0 * NPIX + n;
    const size_t p1 = (size_t)b1 * NPIX + n;

    if (dq == 0)      { o1[p0] = m0 ? 1.0f : 0.0f;          o1[p1] = m1 ? 1.0f : 0.0f; }
    else if (dq == 1) { o2[p0] = m0 ? (float)cls0 : 20.0f;  o2[p1] = m1 ? (float)cls1 : 20.0f; }
    else if (dq == 2) { o3[p0] = vmin0;                     o3[p1] = vmin1; }
    else              { o4[p0] = (float)cls0;               o4[p1] = (float)cls1; }

    // one-hot * mask: dq lanes split the 21 columns (6+6+6+3)
    #pragma unroll
    for (int j = 0; j < 6; ++j) {
        const int c = dq * 6 + j;
        if (c < NCAT) {
            o0[p0 * NCAT + c] = (m0 && c == cls0) ? 1.0f : 0.0f;
            o0[p1 * NCAT + c] = (m1 && c == cls1) ? 1.0f : 0.0f;
        }
    }
}

extern "C" void kernel_launch(void* const* d_in, const int* in_sizes, int n_in,
                              void* d_out, int out_size, void* d_ws, size_t ws_size,
                              hipStream_t stream) {
    const float* frame = (const float*)d_in[0];
    const float* tmpl  = (const float*)d_in[1];
    const int*   tcls  = (const int*)d_in[2];
    float* outp = (float*)d_out;
    nn_openset_kernel<<<NPIX / P, 256, 0, stream>>>(frame, tmpl, tcls, outp);
}